// Round 9
// baseline (313.692 us; speedup 1.0000x reference)
//
#include <hip/hip_runtime.h>
#include <hip/hip_bf16.h>
#include <stdint.h>

#define N_NODES 50000
#define N_EDGES 600000
#define D 128
#define BM 16                 // rows per block (50000 = 16 * 3125, exact)
#define NBLK (N_NODES / BM)   // 3125
#define CAP 64                // fixed CSR capacity per node (P(deg>56) ~ 1e-30)
#define DUMMY N_NODES         // index of the all-zeros row (fits in ushort)
#define NBUCK 391             // ceil(N_NODES / 128)
#define BCAP 2048             // entries per bucket (mean 1536, sigma~39 -> 13 sigma)

typedef __attribute__((ext_vector_type(8))) short bf16x8_t;    // 8 bf16 (4 VGPRs)
typedef __attribute__((ext_vector_type(8))) ushort ushort8_t;  // 8 u16 (16B load)
typedef __attribute__((ext_vector_type(4))) float f32x4;

__device__ __forceinline__ float bf2f(ushort u) {
    union { uint32_t u; float f; } v;
    v.u = ((uint32_t)u) << 16;
    return v.f;
}
__device__ __forceinline__ ushort f2bf(float f) {
    union { float f; uint32_t u; } v; v.f = f;
    uint32_t u = v.u;
    return (ushort)((u + 0x7fffu + ((u >> 16) & 1u)) >> 16);  // RNE
}

// ---------------- init: zero bucket counters + dummy rows ----------------

__global__ __launch_bounds__(256) void init_kernel(int* __restrict__ bkt_cnt,
                                                   ushort* __restrict__ ibuf,
                                                   ushort* __restrict__ hbuf) {
    int i = blockIdx.x * 256 + threadIdx.x;
    if (i < NBUCK) bkt_cnt[i] = 0;
    if (i < D) {
        ibuf[(size_t)DUMMY * D + i] = 0;
        hbuf[(size_t)DUMMY * D + i] = 0;
    }
}

// ---------------- Pass A: bucket edges (append-sequential, no RMW amp) + cvt ----

__global__ __launch_bounds__(256) void scatter_prep(const int* __restrict__ src,
                                                    const int* __restrict__ dst,
                                                    int* __restrict__ bkt_cnt,
                                                    uint32_t* __restrict__ bkt,
                                                    const float* __restrict__ in,
                                                    ushort* __restrict__ ibuf,
                                                    const float* __restrict__ W1a,
                                                    const float* __restrict__ W1b,
                                                    const float* __restrict__ W2a,
                                                    const float* __restrict__ W2b,
                                                    ushort* __restrict__ wbuf) {
    int tid = blockIdx.x * 256 + threadIdx.x;
    int stride = gridDim.x * 256;
    // edge -> coarse bucket (dst>>7), packed entry (dst&127)<<16 | src
    for (int e = tid; e < N_EDGES; e += stride) {
        int d = dst[e];
        int b = d >> 7;
        int slot = atomicAdd(&bkt_cnt[b], 1);
        bkt[((size_t)b << 11) + slot] = (uint32_t)src[e] | ((uint32_t)(d & 127) << 16);
    }
    // cvt inputs f32 -> bf16
    const int total4 = N_NODES * 32;
    for (int i = tid; i < total4; i += stride) {
        float4 v = ((const float4*)in)[i];
        ushort4 o;
        o.x = f2bf(v.x); o.y = f2bf(v.y); o.z = f2bf(v.z); o.w = f2bf(v.w);
        ((ushort4*)ibuf)[i] = o;
    }
    // Wt[mat][n][k] = W[mat][k][n]
    for (int idx = tid; idx < 65536; idx += stride) {
        const float* srcs[4] = {W1a, W1b, W2a, W2b};
        int mat = idx >> 14;
        int n = (idx >> 7) & 127;
        int k = idx & 127;
        wbuf[idx] = f2bf(srcs[mat][k * 128 + n]);
    }
}

// ---------------- Pass B: bucket -> fixed-slot ushort CSR (block-private region) ----

__global__ __launch_bounds__(256) void bucket2csr(const int* __restrict__ bkt_cnt,
                                                  const uint32_t* __restrict__ bkt,
                                                  ushort* __restrict__ csr,
                                                  int* __restrict__ cur) {
    __shared__ int cnt[128];
    int tid = threadIdx.x;
    int bid = blockIdx.x;
    int base = bid << 7;
    if (tid < 128) cnt[tid] = 0;
    __syncthreads();
    int n = bkt_cnt[bid];
    const uint32_t* bp = bkt + ((size_t)bid << 11);
    for (int i = tid; i < n; i += 256) {
        uint32_t e = bp[i];
        int dl = e >> 16;
        int s = atomicAdd(&cnt[dl], 1);
        csr[((size_t)(base + dl) << 6) + s] = (ushort)(e & 0xffffu);
    }
    __syncthreads();
    if (tid < 128 && base + tid < N_NODES)
        cur[base + tid] = ((base + tid) << 6) + cnt[tid];
}

// ---------------- Fused GIN layer: gather + 2-layer MLP (MFMA bf16) ----------------
// Block = 16 nodes, 256 threads (4 waves). Grid covers N_NODES exactly.
// Gather: 16 threads/row, 8 elems each; fixed-slot ushort CSR (row<<6).
//   Full ushort8 groups (8 independent b128 gathers in flight) + one
//   branch-free masked tail group (unwritten slots -> DUMMY zero row, L1-hot).
// MFMA: wave w -> rows [0,16) x cols [w*32, +32); A-frag lane l (m=l&15,g=l>>4):
//   xs[m][32c+8g..]; B same k-map from Wt; C/D: col=l&15, row=g*4+r.
// Layer-1 epilogue staged through LDS -> b128 row stores (no write amplification).

template <int OUT_BF16>
__global__ __launch_bounds__(256) void gin_layer(const ushort* __restrict__ h,
                                                 const int* __restrict__ cur,
                                                 const ushort* __restrict__ csr,
                                                 const ushort* __restrict__ Wat,
                                                 const float* __restrict__ ba,
                                                 const ushort* __restrict__ Wbt,
                                                 const float* __restrict__ bb,
                                                 void* __restrict__ outp) {
    __shared__ ushort xs[BM][136];
    __shared__ ushort hs[BM][136];
    int tid = threadIdx.x;
    int row0 = blockIdx.x * BM;

    // ---- Phase 1: gather x = h[row] + sum_{nbr} h[nbr] ----
    {
        int r = tid >> 4;          // 0..15 local row
        int q = tid & 15;          // 8-elem slice
        int row = row0 + r;
        const ushort* hq = h + q * 8;
        float acc[8];
        {
            bf16x8_t t0 = *(const bf16x8_t*)(hq + (size_t)row * D);
            #pragma unroll
            for (int j = 0; j < 8; ++j) acc[j] = bf2f((ushort)t0[j]);
        }
        int sbase = row << 6;                       // fixed-slot offset
        int n = cur[row] - sbase;                   // degree
        const ushort* cp = csr + sbase;             // 128B-aligned
        int full = n >> 3;
        int rem = n & 7;
        // full groups of 8 (pipelined index loads)
        ushort8_t ii = *(const ushort8_t*)cp;       // safe: CAP >= 8
        for (int it = 0; it < full; ++it) {
            ushort8_t ci = ii;
            int nx = (it + 1 < full) ? (it + 1) * 8 : it * 8;
            ii = *(const ushort8_t*)(cp + nx);
            bf16x8_t g0 = *(const bf16x8_t*)(hq + (size_t)ci[0] * D);
            bf16x8_t g1 = *(const bf16x8_t*)(hq + (size_t)ci[1] * D);
            bf16x8_t g2 = *(const bf16x8_t*)(hq + (size_t)ci[2] * D);
            bf16x8_t g3 = *(const bf16x8_t*)(hq + (size_t)ci[3] * D);
            bf16x8_t g4 = *(const bf16x8_t*)(hq + (size_t)ci[4] * D);
            bf16x8_t g5 = *(const bf16x8_t*)(hq + (size_t)ci[5] * D);
            bf16x8_t g6 = *(const bf16x8_t*)(hq + (size_t)ci[6] * D);
            bf16x8_t g7 = *(const bf16x8_t*)(hq + (size_t)ci[7] * D);
            #pragma unroll
            for (int j = 0; j < 8; ++j) {
                acc[j] += ((bf2f((ushort)g0[j]) + bf2f((ushort)g1[j]))
                         + (bf2f((ushort)g2[j]) + bf2f((ushort)g3[j])))
                        + ((bf2f((ushort)g4[j]) + bf2f((ushort)g5[j]))
                         + (bf2f((ushort)g6[j]) + bf2f((ushort)g7[j])));
            }
        }
        // branch-free masked tail (slots [full*8, full*8+8) exist: deg<=56)
        {
            ushort8_t ci = *(const ushort8_t*)(cp + full * 8);
            int idx[8];
            #pragma unroll
            for (int j = 0; j < 8; ++j) idx[j] = (j < rem) ? (int)ci[j] : DUMMY;
            bf16x8_t g0 = *(const bf16x8_t*)(hq + (size_t)idx[0] * D);
            bf16x8_t g1 = *(const bf16x8_t*)(hq + (size_t)idx[1] * D);
            bf16x8_t g2 = *(const bf16x8_t*)(hq + (size_t)idx[2] * D);
            bf16x8_t g3 = *(const bf16x8_t*)(hq + (size_t)idx[3] * D);
            bf16x8_t g4 = *(const bf16x8_t*)(hq + (size_t)idx[4] * D);
            bf16x8_t g5 = *(const bf16x8_t*)(hq + (size_t)idx[5] * D);
            bf16x8_t g6 = *(const bf16x8_t*)(hq + (size_t)idx[6] * D);
            bf16x8_t g7 = *(const bf16x8_t*)(hq + (size_t)idx[7] * D);
            #pragma unroll
            for (int j = 0; j < 8; ++j) {
                acc[j] += ((bf2f((ushort)g0[j]) + bf2f((ushort)g1[j]))
                         + (bf2f((ushort)g2[j]) + bf2f((ushort)g3[j])))
                        + ((bf2f((ushort)g4[j]) + bf2f((ushort)g5[j]))
                         + (bf2f((ushort)g6[j]) + bf2f((ushort)g7[j])));
            }
        }
        bf16x8_t o0;
        #pragma unroll
        for (int j = 0; j < 8; ++j) o0[j] = (short)f2bf(acc[j]);
        *(bf16x8_t*)&xs[r][q * 8] = o0;
    }
    __syncthreads();

    int w = tid >> 6;          // wave 0..3 -> col strip
    int l = tid & 63;
    int lr = l & 15;
    int g = l >> 4;
    int ch = w * 32;

    // ---- GEMM1: hs = relu(xs @ Wa + ba) ----
    {
        bf16x8_t a[4];
        #pragma unroll
        for (int c = 0; c < 4; ++c)
            a[c] = *(const bf16x8_t*)&xs[lr][32 * c + 8 * g];

        #pragma unroll
        for (int nt = 0; nt < 2; ++nt) {
            int col = ch + 16 * nt + lr;
            f32x4 c4 = {0.f, 0.f, 0.f, 0.f};
            const ushort* wrow = Wat + (size_t)col * D + g * 8;
            #pragma unroll
            for (int c = 0; c < 4; ++c) {
                bf16x8_t b = *(const bf16x8_t*)(wrow + 32 * c);
                c4 = __builtin_amdgcn_mfma_f32_16x16x32_bf16(a[c], b, c4, 0, 0, 0);
            }
            float bv = ba[col];
            #pragma unroll
            for (int r = 0; r < 4; ++r) {
                float v = fmaxf(c4[r] + bv, 0.f);
                hs[g * 4 + r][col] = f2bf(v);
            }
        }
    }
    __syncthreads();

    // ---- GEMM2: out = hs @ Wb + bb ----
    {
        bf16x8_t a2[4];
        #pragma unroll
        for (int c = 0; c < 4; ++c)
            a2[c] = *(const bf16x8_t*)&hs[lr][32 * c + 8 * g];

        #pragma unroll
        for (int nt = 0; nt < 2; ++nt) {
            int col = ch + 16 * nt + lr;
            f32x4 c4 = {0.f, 0.f, 0.f, 0.f};
            const ushort* wrow = Wbt + (size_t)col * D + g * 8;
            #pragma unroll
            for (int c = 0; c < 4; ++c) {
                bf16x8_t b = *(const bf16x8_t*)(wrow + 32 * c);
                c4 = __builtin_amdgcn_mfma_f32_16x16x32_bf16(a2[c], b, c4, 0, 0, 0);
            }
            float bv = bb[col];
            #pragma unroll
            for (int r = 0; r < 4; ++r) {
                int row = row0 + g * 4 + r;
                float v = c4[r] + bv;
                if (OUT_BF16) {
                    // stage relu'd bf16 into (dead) xs for coalesced row stores
                    xs[g * 4 + r][col] = f2bf(fmaxf(v, 0.f));
                } else {
                    ((float*)outp)[(size_t)row * D + col] = v;
                }
            }
        }
    }
    if (OUT_BF16) {
        __syncthreads();
        int rr = tid >> 4;
        int qq = tid & 15;
        *(bf16x8_t*)((ushort*)outp + (size_t)(row0 + rr) * D + qq * 8) =
            *(const bf16x8_t*)&xs[rr][qq * 8];
    }
}

// ---------------- launch ----------------

extern "C" void kernel_launch(void* const* d_in, const int* in_sizes, int n_in,
                              void* d_out, int out_size, void* d_ws, size_t ws_size,
                              hipStream_t stream) {
    const float* inputs = (const float*)d_in[0];
    const int* src = (const int*)d_in[1];
    const int* dst = (const int*)d_in[2];
    const float* W1a = (const float*)d_in[3];
    const float* b1a = (const float*)d_in[4];
    const float* W1b = (const float*)d_in[5];
    const float* b1b = (const float*)d_in[6];
    const float* W2a = (const float*)d_in[7];
    const float* b2a = (const float*)d_in[8];
    const float* W2b = (const float*)d_in[9];
    const float* b2b = (const float*)d_in[10];
    float* out = (float*)d_out;

    // workspace: [cur N][bkt_cnt NBUCK][bkt NBUCK*BCAP u32][csr N*CAP u16][w][i][h]
    int* cur = (int*)d_ws;                              // N ints
    int* bkt_cnt = cur + N_NODES;                       // NBUCK
    uint32_t* bkt = (uint32_t*)(((uintptr_t)(bkt_cnt + NBUCK) + 255)
                                & ~(uintptr_t)255);     // NBUCK*BCAP
    ushort* csr = (ushort*)(bkt + (size_t)NBUCK * BCAP);
    ushort* wbuf = (ushort*)(((uintptr_t)(csr + (size_t)N_NODES * CAP + 64) + 255)
                             & ~(uintptr_t)255);
    ushort* W1at = wbuf;                                // [128][128] each, transposed
    ushort* W1bt = wbuf + 16384;
    ushort* W2at = wbuf + 2 * 16384;
    ushort* W2bt = wbuf + 3 * 16384;
    ushort* ibuf = wbuf + 4 * 16384;                    // [N_NODES+1][128] bf16
    ushort* hbuf = ibuf + (size_t)(N_NODES + 1) * D;    // [N_NODES+1][128] bf16

    init_kernel<<<2, 256, 0, stream>>>(bkt_cnt, ibuf, hbuf);
    scatter_prep<<<2048, 256, 0, stream>>>(src, dst, bkt_cnt, bkt, inputs, ibuf,
                                           W1a, W1b, W2a, W2b, wbuf);
    bucket2csr<<<NBUCK, 256, 0, stream>>>(bkt_cnt, bkt, csr, cur);

    gin_layer<1><<<NBLK, 256, 0, stream>>>(ibuf, cur, csr,
                                           W1at, b1a, W1bt, b1b, (void*)hbuf);
    gin_layer<0><<<NBLK, 256, 0, stream>>>(hbuf, cur, csr,
                                           W2at, b2a, W2bt, b2b, (void*)out);
}

// Round 10
// 143.945 us; speedup vs baseline: 2.1793x; 2.1793x over previous
//
#include <hip/hip_runtime.h>
#include <hip/hip_bf16.h>
#include <stdint.h>

#define N_NODES 50000
#define N_EDGES 600000
#define D 128
#define BM 16                 // rows per block (50000 = 16 * 3125, exact)
#define NBLK (N_NODES / BM)   // 3125
#define CAP 64                // fixed CSR capacity per node (P(deg>56) ~ 1e-30)
#define DUMMY N_NODES         // index of the all-zeros row (fits in ushort)
#define NBUCK 391             // ceil(N_NODES / 128)
#define NSHARD 32             // counter shards per bucket (contention fix)
#define SCAP 128              // entries per (bucket,shard): mean 48, ~12 sigma

typedef __attribute__((ext_vector_type(8))) short bf16x8_t;    // 8 bf16 (4 VGPRs)
typedef __attribute__((ext_vector_type(8))) ushort ushort8_t;  // 8 u16 (16B load)
typedef __attribute__((ext_vector_type(4))) float f32x4;

__device__ __forceinline__ float bf2f(ushort u) {
    union { uint32_t u; float f; } v;
    v.u = ((uint32_t)u) << 16;
    return v.f;
}
__device__ __forceinline__ ushort f2bf(float f) {
    union { float f; uint32_t u; } v; v.f = f;
    uint32_t u = v.u;
    return (ushort)((u + 0x7fffu + ((u >> 16) & 1u)) >> 16);  // RNE
}

// ---------------- init: zero sharded bucket counters + dummy rows ----------------

__global__ __launch_bounds__(256) void init_kernel(int* __restrict__ bkt_cnt,
                                                   ushort* __restrict__ ibuf,
                                                   ushort* __restrict__ hbuf) {
    int i = blockIdx.x * 256 + threadIdx.x;
    if (i < NBUCK * NSHARD) bkt_cnt[i] = 0;
    if (i < D) {
        ibuf[(size_t)DUMMY * D + i] = 0;
        hbuf[(size_t)DUMMY * D + i] = 0;
    }
}

// ---------------- Pass A: bucket edges into sharded append-lists + cvt ----------

__global__ __launch_bounds__(256) void scatter_prep(const int* __restrict__ src,
                                                    const int* __restrict__ dst,
                                                    int* __restrict__ bkt_cnt,
                                                    uint32_t* __restrict__ bkt,
                                                    const float* __restrict__ in,
                                                    ushort* __restrict__ ibuf,
                                                    const float* __restrict__ W1a,
                                                    const float* __restrict__ W1b,
                                                    const float* __restrict__ W2a,
                                                    const float* __restrict__ W2b,
                                                    ushort* __restrict__ wbuf) {
    int tid = blockIdx.x * 256 + threadIdx.x;
    int stride = gridDim.x * 256;
    int shard = blockIdx.x & (NSHARD - 1);
    // edge -> (bucket,shard) append; packed entry (dst&127)<<16 | src
    for (int e = tid; e < N_EDGES; e += stride) {
        int d = dst[e];
        int ci = ((d >> 7) << 5) | shard;            // (bucket<<5)|shard
        int slot = atomicAdd(&bkt_cnt[ci], 1);
        bkt[((size_t)ci << 7) + slot] = (uint32_t)src[e] | ((uint32_t)(d & 127) << 16);
    }
    // cvt inputs f32 -> bf16
    const int total4 = N_NODES * 32;
    for (int i = tid; i < total4; i += stride) {
        float4 v = ((const float4*)in)[i];
        ushort4 o;
        o.x = f2bf(v.x); o.y = f2bf(v.y); o.z = f2bf(v.z); o.w = f2bf(v.w);
        ((ushort4*)ibuf)[i] = o;
    }
    // Wt[mat][n][k] = W[mat][k][n]
    for (int idx = tid; idx < 65536; idx += stride) {
        const float* srcs[4] = {W1a, W1b, W2a, W2b};
        int mat = idx >> 14;
        int n = (idx >> 7) & 127;
        int k = idx & 127;
        wbuf[idx] = f2bf(srcs[mat][k * 128 + n]);
    }
}

// ---------------- Pass B: sharded buckets -> fixed-slot ushort CSR --------------

__global__ __launch_bounds__(256) void bucket2csr(const int* __restrict__ bkt_cnt,
                                                  const uint32_t* __restrict__ bkt,
                                                  ushort* __restrict__ csr,
                                                  int* __restrict__ cur) {
    __shared__ int cnt[128];
    int tid = threadIdx.x;
    int bid = blockIdx.x;
    int base = bid << 7;
    if (tid < 128) cnt[tid] = 0;
    __syncthreads();
    for (int sh = 0; sh < NSHARD; ++sh) {
        int ci = (bid << 5) | sh;
        int n = bkt_cnt[ci];
        const uint32_t* bp = bkt + ((size_t)ci << 7);
        for (int i = tid; i < n; i += 256) {
            uint32_t e = bp[i];
            int dl = e >> 16;
            int s = atomicAdd(&cnt[dl], 1);
            csr[((size_t)(base + dl) << 6) + s] = (ushort)(e & 0xffffu);
        }
    }
    __syncthreads();
    if (tid < 128 && base + tid < N_NODES)
        cur[base + tid] = ((base + tid) << 6) + cnt[tid];
}

// ---------------- Fused GIN layer: gather + 2-layer MLP (MFMA bf16) ----------------
// Block = 16 nodes, 256 threads (4 waves). Grid covers N_NODES exactly.
// Gather: 16 threads/row, 8 elems each; fixed-slot ushort CSR (row<<6).
//   Full ushort8 groups (8 independent b128 gathers in flight) + one
//   branch-free masked tail group (unwritten slots -> DUMMY zero row, L1-hot).
// MFMA: wave w -> rows [0,16) x cols [w*32, +32); A-frag lane l (m=l&15,g=l>>4):
//   xs[m][32c+8g..]; B same k-map from Wt; C/D: col=l&15, row=g*4+r.
// Layer-1 epilogue staged through LDS -> b128 row stores (no write amplification).

template <int OUT_BF16>
__global__ __launch_bounds__(256) void gin_layer(const ushort* __restrict__ h,
                                                 const int* __restrict__ cur,
                                                 const ushort* __restrict__ csr,
                                                 const ushort* __restrict__ Wat,
                                                 const float* __restrict__ ba,
                                                 const ushort* __restrict__ Wbt,
                                                 const float* __restrict__ bb,
                                                 void* __restrict__ outp) {
    __shared__ ushort xs[BM][136];
    __shared__ ushort hs[BM][136];
    int tid = threadIdx.x;
    int row0 = blockIdx.x * BM;

    // ---- Phase 1: gather x = h[row] + sum_{nbr} h[nbr] ----
    {
        int r = tid >> 4;          // 0..15 local row
        int q = tid & 15;          // 8-elem slice
        int row = row0 + r;
        const ushort* hq = h + q * 8;
        float acc[8];
        {
            bf16x8_t t0 = *(const bf16x8_t*)(hq + (size_t)row * D);
            #pragma unroll
            for (int j = 0; j < 8; ++j) acc[j] = bf2f((ushort)t0[j]);
        }
        int sbase = row << 6;                       // fixed-slot offset
        int n = cur[row] - sbase;                   // degree
        const ushort* cp = csr + sbase;             // 128B-aligned
        int full = n >> 3;
        int rem = n & 7;
        // full groups of 8 (pipelined index loads)
        ushort8_t ii = *(const ushort8_t*)cp;       // safe: CAP >= 8
        for (int it = 0; it < full; ++it) {
            ushort8_t ci = ii;
            int nx = (it + 1 < full) ? (it + 1) * 8 : it * 8;
            ii = *(const ushort8_t*)(cp + nx);
            bf16x8_t g0 = *(const bf16x8_t*)(hq + (size_t)ci[0] * D);
            bf16x8_t g1 = *(const bf16x8_t*)(hq + (size_t)ci[1] * D);
            bf16x8_t g2 = *(const bf16x8_t*)(hq + (size_t)ci[2] * D);
            bf16x8_t g3 = *(const bf16x8_t*)(hq + (size_t)ci[3] * D);
            bf16x8_t g4 = *(const bf16x8_t*)(hq + (size_t)ci[4] * D);
            bf16x8_t g5 = *(const bf16x8_t*)(hq + (size_t)ci[5] * D);
            bf16x8_t g6 = *(const bf16x8_t*)(hq + (size_t)ci[6] * D);
            bf16x8_t g7 = *(const bf16x8_t*)(hq + (size_t)ci[7] * D);
            #pragma unroll
            for (int j = 0; j < 8; ++j) {
                acc[j] += ((bf2f((ushort)g0[j]) + bf2f((ushort)g1[j]))
                         + (bf2f((ushort)g2[j]) + bf2f((ushort)g3[j])))
                        + ((bf2f((ushort)g4[j]) + bf2f((ushort)g5[j]))
                         + (bf2f((ushort)g6[j]) + bf2f((ushort)g7[j])));
            }
        }
        // branch-free masked tail (slots [full*8, full*8+8) exist: deg<=56)
        {
            ushort8_t ci = *(const ushort8_t*)(cp + full * 8);
            int idx[8];
            #pragma unroll
            for (int j = 0; j < 8; ++j) idx[j] = (j < rem) ? (int)ci[j] : DUMMY;
            bf16x8_t g0 = *(const bf16x8_t*)(hq + (size_t)idx[0] * D);
            bf16x8_t g1 = *(const bf16x8_t*)(hq + (size_t)idx[1] * D);
            bf16x8_t g2 = *(const bf16x8_t*)(hq + (size_t)idx[2] * D);
            bf16x8_t g3 = *(const bf16x8_t*)(hq + (size_t)idx[3] * D);
            bf16x8_t g4 = *(const bf16x8_t*)(hq + (size_t)idx[4] * D);
            bf16x8_t g5 = *(const bf16x8_t*)(hq + (size_t)idx[5] * D);
            bf16x8_t g6 = *(const bf16x8_t*)(hq + (size_t)idx[6] * D);
            bf16x8_t g7 = *(const bf16x8_t*)(hq + (size_t)idx[7] * D);
            #pragma unroll
            for (int j = 0; j < 8; ++j) {
                acc[j] += ((bf2f((ushort)g0[j]) + bf2f((ushort)g1[j]))
                         + (bf2f((ushort)g2[j]) + bf2f((ushort)g3[j])))
                        + ((bf2f((ushort)g4[j]) + bf2f((ushort)g5[j]))
                         + (bf2f((ushort)g6[j]) + bf2f((ushort)g7[j])));
            }
        }
        bf16x8_t o0;
        #pragma unroll
        for (int j = 0; j < 8; ++j) o0[j] = (short)f2bf(acc[j]);
        *(bf16x8_t*)&xs[r][q * 8] = o0;
    }
    __syncthreads();

    int w = tid >> 6;          // wave 0..3 -> col strip
    int l = tid & 63;
    int lr = l & 15;
    int g = l >> 4;
    int ch = w * 32;

    // ---- GEMM1: hs = relu(xs @ Wa + ba) ----
    {
        bf16x8_t a[4];
        #pragma unroll
        for (int c = 0; c < 4; ++c)
            a[c] = *(const bf16x8_t*)&xs[lr][32 * c + 8 * g];

        #pragma unroll
        for (int nt = 0; nt < 2; ++nt) {
            int col = ch + 16 * nt + lr;
            f32x4 c4 = {0.f, 0.f, 0.f, 0.f};
            const ushort* wrow = Wat + (size_t)col * D + g * 8;
            #pragma unroll
            for (int c = 0; c < 4; ++c) {
                bf16x8_t b = *(const bf16x8_t*)(wrow + 32 * c);
                c4 = __builtin_amdgcn_mfma_f32_16x16x32_bf16(a[c], b, c4, 0, 0, 0);
            }
            float bv = ba[col];
            #pragma unroll
            for (int r = 0; r < 4; ++r) {
                float v = fmaxf(c4[r] + bv, 0.f);
                hs[g * 4 + r][col] = f2bf(v);
            }
        }
    }
    __syncthreads();

    // ---- GEMM2: out = hs @ Wb + bb ----
    {
        bf16x8_t a2[4];
        #pragma unroll
        for (int c = 0; c < 4; ++c)
            a2[c] = *(const bf16x8_t*)&hs[lr][32 * c + 8 * g];

        #pragma unroll
        for (int nt = 0; nt < 2; ++nt) {
            int col = ch + 16 * nt + lr;
            f32x4 c4 = {0.f, 0.f, 0.f, 0.f};
            const ushort* wrow = Wbt + (size_t)col * D + g * 8;
            #pragma unroll
            for (int c = 0; c < 4; ++c) {
                bf16x8_t b = *(const bf16x8_t*)(wrow + 32 * c);
                c4 = __builtin_amdgcn_mfma_f32_16x16x32_bf16(a2[c], b, c4, 0, 0, 0);
            }
            float bv = bb[col];
            #pragma unroll
            for (int r = 0; r < 4; ++r) {
                int row = row0 + g * 4 + r;
                float v = c4[r] + bv;
                if (OUT_BF16) {
                    // stage relu'd bf16 into (dead) xs for coalesced row stores
                    xs[g * 4 + r][col] = f2bf(fmaxf(v, 0.f));
                } else {
                    ((float*)outp)[(size_t)row * D + col] = v;
                }
            }
        }
    }
    if (OUT_BF16) {
        __syncthreads();
        int rr = tid >> 4;
        int qq = tid & 15;
        *(bf16x8_t*)((ushort*)outp + (size_t)(row0 + rr) * D + qq * 8) =
            *(const bf16x8_t*)&xs[rr][qq * 8];
    }
}

// ---------------- launch ----------------

extern "C" void kernel_launch(void* const* d_in, const int* in_sizes, int n_in,
                              void* d_out, int out_size, void* d_ws, size_t ws_size,
                              hipStream_t stream) {
    const float* inputs = (const float*)d_in[0];
    const int* src = (const int*)d_in[1];
    const int* dst = (const int*)d_in[2];
    const float* W1a = (const float*)d_in[3];
    const float* b1a = (const float*)d_in[4];
    const float* W1b = (const float*)d_in[5];
    const float* b1b = (const float*)d_in[6];
    const float* W2a = (const float*)d_in[7];
    const float* b2a = (const float*)d_in[8];
    const float* W2b = (const float*)d_in[9];
    const float* b2b = (const float*)d_in[10];
    float* out = (float*)d_out;

    // workspace: [cur N][bkt_cnt NBUCK*NSHARD][bkt NBUCK*NSHARD*SCAP u32]
    //            [csr N*CAP u16][weights][ibuf][hbuf]
    int* cur = (int*)d_ws;                              // N ints
    int* bkt_cnt = cur + N_NODES;                       // NBUCK*NSHARD
    uint32_t* bkt = (uint32_t*)(((uintptr_t)(bkt_cnt + NBUCK * NSHARD) + 255)
                                & ~(uintptr_t)255);     // NBUCK*NSHARD*SCAP
    ushort* csr = (ushort*)(bkt + (size_t)NBUCK * NSHARD * SCAP);
    ushort* wbuf = (ushort*)(((uintptr_t)(csr + (size_t)N_NODES * CAP + 64) + 255)
                             & ~(uintptr_t)255);
    ushort* W1at = wbuf;                                // [128][128] each, transposed
    ushort* W1bt = wbuf + 16384;
    ushort* W2at = wbuf + 2 * 16384;
    ushort* W2bt = wbuf + 3 * 16384;
    ushort* ibuf = wbuf + 4 * 16384;                    // [N_NODES+1][128] bf16
    ushort* hbuf = ibuf + (size_t)(N_NODES + 1) * D;    // [N_NODES+1][128] bf16

    init_kernel<<<(NBUCK * NSHARD + 255) / 256, 256, 0, stream>>>(bkt_cnt, ibuf, hbuf);
    scatter_prep<<<2048, 256, 0, stream>>>(src, dst, bkt_cnt, bkt, inputs, ibuf,
                                           W1a, W1b, W2a, W2b, wbuf);
    bucket2csr<<<NBUCK, 256, 0, stream>>>(bkt_cnt, bkt, csr, cur);

    gin_layer<1><<<NBLK, 256, 0, stream>>>(ibuf, cur, csr,
                                           W1at, b1a, W1bt, b1b, (void*)hbuf);
    gin_layer<0><<<NBLK, 256, 0, stream>>>(hbuf, cur, csr,
                                           W2at, b2a, W2bt, b2b, (void*)out);
}

// Round 11
// 133.153 us; speedup vs baseline: 2.3559x; 1.0810x over previous
//
#include <hip/hip_runtime.h>
#include <hip/hip_bf16.h>
#include <stdint.h>

#define N_NODES 50000
#define N_EDGES 600000
#define D 128
#define BM 16                 // rows per block (50000 = 16 * 3125, exact)
#define NBLK (N_NODES / BM)   // 3125
#define CAP 64                // fixed CSR capacity per node (P(deg>56) ~ 1e-24)
#define DUMMY N_NODES         // index of the all-zeros row (fits in ushort)
#define NBUCK 391             // ceil(N_NODES / 128)
#define NSHARD 32             // counter shards per bucket (contention fix)
#define SCAP 128              // entries per (bucket,shard): mean 48, ~11 sigma

typedef __attribute__((ext_vector_type(8))) short bf16x8_t;    // 8 bf16 (4 VGPRs)
typedef __attribute__((ext_vector_type(8))) ushort ushort8_t;  // 8 u16 (16B load)
typedef __attribute__((ext_vector_type(4))) float f32x4;

__device__ __forceinline__ float bf2f(ushort u) {
    union { uint32_t u; float f; } v;
    v.u = ((uint32_t)u) << 16;
    return v.f;
}
__device__ __forceinline__ ushort f2bf(float f) {
    union { float f; uint32_t u; } v; v.f = f;
    uint32_t u = v.u;
    return (ushort)((u + 0x7fffu + ((u >> 16) & 1u)) >> 16);  // RNE
}

// ---------------- init: zero sharded bucket counters + dummy rows ----------------

__global__ __launch_bounds__(256) void init_kernel(int* __restrict__ bkt_cnt,
                                                   ushort* __restrict__ ibuf,
                                                   ushort* __restrict__ hbuf) {
    int i = blockIdx.x * 256 + threadIdx.x;
    if (i < NBUCK * NSHARD) bkt_cnt[i] = 0;
    if (i < D) {
        ibuf[(size_t)DUMMY * D + i] = 0;
        hbuf[(size_t)DUMMY * D + i] = 0;
    }
}

// ---------------- Pass A: bucket edges into sharded append-lists + cvt ----------

__global__ __launch_bounds__(256) void scatter_prep(const int* __restrict__ src,
                                                    const int* __restrict__ dst,
                                                    int* __restrict__ bkt_cnt,
                                                    uint32_t* __restrict__ bkt,
                                                    const float* __restrict__ in,
                                                    ushort* __restrict__ ibuf,
                                                    const float* __restrict__ W1a,
                                                    const float* __restrict__ W1b,
                                                    const float* __restrict__ W2a,
                                                    const float* __restrict__ W2b,
                                                    ushort* __restrict__ wbuf) {
    int tid = blockIdx.x * 256 + threadIdx.x;
    int stride = gridDim.x * 256;
    int shard = blockIdx.x & (NSHARD - 1);
    // edge -> (bucket,shard) append; packed entry (dst&127)<<16 | src
    for (int e = tid; e < N_EDGES; e += stride) {
        int d = dst[e];
        int ci = ((d >> 7) << 5) | shard;            // (bucket<<5)|shard
        int slot = atomicAdd(&bkt_cnt[ci], 1);
        bkt[((size_t)ci << 7) + slot] = (uint32_t)src[e] | ((uint32_t)(d & 127) << 16);
    }
    // cvt inputs f32 -> bf16
    const int total4 = N_NODES * 32;
    for (int i = tid; i < total4; i += stride) {
        float4 v = ((const float4*)in)[i];
        ushort4 o;
        o.x = f2bf(v.x); o.y = f2bf(v.y); o.z = f2bf(v.z); o.w = f2bf(v.w);
        ((ushort4*)ibuf)[i] = o;
    }
    // Wt[mat][n][k] = W[mat][k][n]
    for (int idx = tid; idx < 65536; idx += stride) {
        const float* srcs[4] = {W1a, W1b, W2a, W2b};
        int mat = idx >> 14;
        int n = (idx >> 7) & 127;
        int k = idx & 127;
        wbuf[idx] = f2bf(srcs[mat][k * 128 + n]);
    }
}

// ---------------- Pass B: sharded buckets -> fixed-slot ushort CSR --------------
// 32 shards processed CONCURRENTLY: 8 lanes per shard (sh=tid&31), LDS cursors.

__global__ __launch_bounds__(256) void bucket2csr(const int* __restrict__ bkt_cnt,
                                                  const uint32_t* __restrict__ bkt,
                                                  ushort* __restrict__ csr,
                                                  int* __restrict__ cur) {
    __shared__ int cnt[128];
    int tid = threadIdx.x;
    int bid = blockIdx.x;
    int base = bid << 7;
    if (tid < 128) cnt[tid] = 0;
    __syncthreads();
    int sh = tid & 31;            // shard
    int li = tid >> 5;            // 0..7 lane within shard
    int ci = (bid << 5) | sh;
    int n = bkt_cnt[ci];
    const uint32_t* bp = bkt + ((size_t)ci << 7);
    for (int i = li; i < n; i += 8) {
        uint32_t e = bp[i];
        int dl = e >> 16;
        int s = atomicAdd(&cnt[dl], 1);
        csr[((size_t)(base + dl) << 6) + s] = (ushort)(e & 0xffffu);
    }
    __syncthreads();
    if (tid < 128 && base + tid < N_NODES)
        cur[base + tid] = ((base + tid) << 6) + cnt[tid];
}

// ---------------- Fused GIN layer: gather + 2-layer MLP (MFMA bf16) ----------------
// Block = 16 nodes, 256 threads (4 waves). Grid covers N_NODES exactly.
// Gather: 16 threads/row, 8 elems each. Batched issue: self + 16 indices loaded
//   upfront, slots >= deg masked to DUMMY (L1-hot zero row), all 16 gathers in
//   flight before first use. Rare remainder loop for deg>16 (P~10%) in masked
//   8-groups. Fixed-slot ushort CSR (row<<6), deg from cur.
// MFMA: wave w -> rows [0,16) x cols [w*32, +32); A-frag lane l (m=l&15,g=l>>4):
//   xs[m][32c+8g..]; B same k-map from Wt; C/D: col=l&15, row=g*4+r.
// Layer-1 epilogue staged through LDS -> b128 row stores (no write amplification).

template <int OUT_BF16>
__global__ __launch_bounds__(256) void gin_layer(const ushort* __restrict__ h,
                                                 const int* __restrict__ cur,
                                                 const ushort* __restrict__ csr,
                                                 const ushort* __restrict__ Wat,
                                                 const float* __restrict__ ba,
                                                 const ushort* __restrict__ Wbt,
                                                 const float* __restrict__ bb,
                                                 void* __restrict__ outp) {
    __shared__ ushort xs[BM][136];
    __shared__ ushort hs[BM][136];
    int tid = threadIdx.x;
    int row0 = blockIdx.x * BM;

    // ---- Phase 1: gather x = h[row] + sum_{nbr} h[nbr] ----
    {
        int r = tid >> 4;          // 0..15 local row
        int q = tid & 15;          // 8-elem slice
        int row = row0 + r;
        const ushort* hq = h + q * 8;
        int sbase = row << 6;
        const ushort* cp = csr + sbase;
        // issue everything independent upfront
        bf16x8_t self = *(const bf16x8_t*)(hq + (size_t)row * D);
        ushort8_t ia = *(const ushort8_t*)cp;        // slots 0-7
        ushort8_t ib = *(const ushort8_t*)(cp + 8);  // slots 8-15
        int n = cur[row] - sbase;                    // degree
        int idx[16];
        #pragma unroll
        for (int j = 0; j < 8; ++j) idx[j] = (j < n) ? (int)ia[j] : DUMMY;
        #pragma unroll
        for (int j = 0; j < 8; ++j) idx[8 + j] = (8 + j < n) ? (int)ib[j] : DUMMY;
        bf16x8_t gg[16];
        #pragma unroll
        for (int t = 0; t < 16; ++t)
            gg[t] = *(const bf16x8_t*)(hq + (size_t)idx[t] * D);
        float acc[8];
        #pragma unroll
        for (int j = 0; j < 8; ++j) acc[j] = bf2f((ushort)self[j]);
        #pragma unroll
        for (int t = 0; t < 16; ++t) {
            #pragma unroll
            for (int j = 0; j < 8; ++j) acc[j] += bf2f((ushort)gg[t][j]);
        }
        // remainder (deg > 16, ~10% of rows): masked 8-groups
        for (int e0 = 16; e0 < n; e0 += 8) {
            ushort8_t ic = *(const ushort8_t*)(cp + e0);   // within CAP
            int jn = n - e0;
            int id2[8];
            #pragma unroll
            for (int j = 0; j < 8; ++j) id2[j] = (j < jn) ? (int)ic[j] : DUMMY;
            bf16x8_t g0 = *(const bf16x8_t*)(hq + (size_t)id2[0] * D);
            bf16x8_t g1 = *(const bf16x8_t*)(hq + (size_t)id2[1] * D);
            bf16x8_t g2 = *(const bf16x8_t*)(hq + (size_t)id2[2] * D);
            bf16x8_t g3 = *(const bf16x8_t*)(hq + (size_t)id2[3] * D);
            bf16x8_t g4 = *(const bf16x8_t*)(hq + (size_t)id2[4] * D);
            bf16x8_t g5 = *(const bf16x8_t*)(hq + (size_t)id2[5] * D);
            bf16x8_t g6 = *(const bf16x8_t*)(hq + (size_t)id2[6] * D);
            bf16x8_t g7 = *(const bf16x8_t*)(hq + (size_t)id2[7] * D);
            #pragma unroll
            for (int j = 0; j < 8; ++j) {
                acc[j] += ((bf2f((ushort)g0[j]) + bf2f((ushort)g1[j]))
                         + (bf2f((ushort)g2[j]) + bf2f((ushort)g3[j])))
                        + ((bf2f((ushort)g4[j]) + bf2f((ushort)g5[j]))
                         + (bf2f((ushort)g6[j]) + bf2f((ushort)g7[j])));
            }
        }
        bf16x8_t o0;
        #pragma unroll
        for (int j = 0; j < 8; ++j) o0[j] = (short)f2bf(acc[j]);
        *(bf16x8_t*)&xs[r][q * 8] = o0;
    }
    __syncthreads();

    int w = tid >> 6;          // wave 0..3 -> col strip
    int l = tid & 63;
    int lr = l & 15;
    int g = l >> 4;
    int ch = w * 32;

    // ---- GEMM1: hs = relu(xs @ Wa + ba) ----
    {
        bf16x8_t a[4];
        #pragma unroll
        for (int c = 0; c < 4; ++c)
            a[c] = *(const bf16x8_t*)&xs[lr][32 * c + 8 * g];

        #pragma unroll
        for (int nt = 0; nt < 2; ++nt) {
            int col = ch + 16 * nt + lr;
            f32x4 c4 = {0.f, 0.f, 0.f, 0.f};
            const ushort* wrow = Wat + (size_t)col * D + g * 8;
            #pragma unroll
            for (int c = 0; c < 4; ++c) {
                bf16x8_t b = *(const bf16x8_t*)(wrow + 32 * c);
                c4 = __builtin_amdgcn_mfma_f32_16x16x32_bf16(a[c], b, c4, 0, 0, 0);
            }
            float bv = ba[col];
            #pragma unroll
            for (int r = 0; r < 4; ++r) {
                float v = fmaxf(c4[r] + bv, 0.f);
                hs[g * 4 + r][col] = f2bf(v);
            }
        }
    }
    __syncthreads();

    // ---- GEMM2: out = hs @ Wb + bb ----
    {
        bf16x8_t a2[4];
        #pragma unroll
        for (int c = 0; c < 4; ++c)
            a2[c] = *(const bf16x8_t*)&hs[lr][32 * c + 8 * g];

        #pragma unroll
        for (int nt = 0; nt < 2; ++nt) {
            int col = ch + 16 * nt + lr;
            f32x4 c4 = {0.f, 0.f, 0.f, 0.f};
            const ushort* wrow = Wbt + (size_t)col * D + g * 8;
            #pragma unroll
            for (int c = 0; c < 4; ++c) {
                bf16x8_t b = *(const bf16x8_t*)(wrow + 32 * c);
                c4 = __builtin_amdgcn_mfma_f32_16x16x32_bf16(a2[c], b, c4, 0, 0, 0);
            }
            float bv = bb[col];
            #pragma unroll
            for (int r = 0; r < 4; ++r) {
                int row = row0 + g * 4 + r;
                float v = c4[r] + bv;
                if (OUT_BF16) {
                    // stage relu'd bf16 into (dead) xs for coalesced row stores
                    xs[g * 4 + r][col] = f2bf(fmaxf(v, 0.f));
                } else {
                    ((float*)outp)[(size_t)row * D + col] = v;
                }
            }
        }
    }
    if (OUT_BF16) {
        __syncthreads();
        int rr = tid >> 4;
        int qq = tid & 15;
        *(bf16x8_t*)((ushort*)outp + (size_t)(row0 + rr) * D + qq * 8) =
            *(const bf16x8_t*)&xs[rr][qq * 8];
    }
}

// ---------------- launch ----------------

extern "C" void kernel_launch(void* const* d_in, const int* in_sizes, int n_in,
                              void* d_out, int out_size, void* d_ws, size_t ws_size,
                              hipStream_t stream) {
    const float* inputs = (const float*)d_in[0];
    const int* src = (const int*)d_in[1];
    const int* dst = (const int*)d_in[2];
    const float* W1a = (const float*)d_in[3];
    const float* b1a = (const float*)d_in[4];
    const float* W1b = (const float*)d_in[5];
    const float* b1b = (const float*)d_in[6];
    const float* W2a = (const float*)d_in[7];
    const float* b2a = (const float*)d_in[8];
    const float* W2b = (const float*)d_in[9];
    const float* b2b = (const float*)d_in[10];
    float* out = (float*)d_out;

    // workspace: [cur N][bkt_cnt NBUCK*NSHARD][bkt NBUCK*NSHARD*SCAP u32]
    //            [csr N*CAP u16][weights][ibuf][hbuf]
    int* cur = (int*)d_ws;                              // N ints
    int* bkt_cnt = cur + N_NODES;                       // NBUCK*NSHARD
    uint32_t* bkt = (uint32_t*)(((uintptr_t)(bkt_cnt + NBUCK * NSHARD) + 255)
                                & ~(uintptr_t)255);     // NBUCK*NSHARD*SCAP
    ushort* csr = (ushort*)(bkt + (size_t)NBUCK * NSHARD * SCAP);
    ushort* wbuf = (ushort*)(((uintptr_t)(csr + (size_t)N_NODES * CAP + 64) + 255)
                             & ~(uintptr_t)255);
    ushort* W1at = wbuf;                                // [128][128] each, transposed
    ushort* W1bt = wbuf + 16384;
    ushort* W2at = wbuf + 2 * 16384;
    ushort* W2bt = wbuf + 3 * 16384;
    ushort* ibuf = wbuf + 4 * 16384;                    // [N_NODES+1][128] bf16
    ushort* hbuf = ibuf + (size_t)(N_NODES + 1) * D;    // [N_NODES+1][128] bf16

    init_kernel<<<(NBUCK * NSHARD + 255) / 256, 256, 0, stream>>>(bkt_cnt, ibuf, hbuf);
    scatter_prep<<<2048, 256, 0, stream>>>(src, dst, bkt_cnt, bkt, inputs, ibuf,
                                           W1a, W1b, W2a, W2b, wbuf);
    bucket2csr<<<NBUCK, 256, 0, stream>>>(bkt_cnt, bkt, csr, cur);

    gin_layer<1><<<NBLK, 256, 0, stream>>>(ibuf, cur, csr,
                                           W1at, b1a, W1bt, b1b, (void*)hbuf);
    gin_layer<0><<<NBLK, 256, 0, stream>>>(hbuf, cur, csr,
                                           W2at, b2a, W2bt, b2b, (void*)out);
}